// Round 21
// baseline (810.625 us; speedup 1.0000x reference)
//
#include <hip/hip_runtime.h>

// LGA3: 3 chained local-guided-aggregation passes, rolling-accumulator stencil.
// R13 d-split shell (4-wave 256-thr independent blocks, 32 d each, DPT=8,
// double-buffered cost LDS via global_load_lds, 75 weights batch-loaded to
// registers, one __syncthreads per iter) with:
//   - HSEG=16 (RITER=20): h-halo overhead per output row 1.5x -> 1.25x
//   - rotation-free accumulators: 5-way unrolled body, logical slot s at
//     iter r=rb+u lives in physical acc[(u+s)%5] (static indices, no movs);
//     the slot written at iter r is zeroed in place.
// cost [B=2, D=64, H=384, W=768] fp32, weights [B, 75, H, W] fp32.
// out[b,d,h,w] = sum_{i,j in 5x5} w0*c[d-1,h+i-2,w+j-2] + w1*c[d,..] + w2*c[d+1,..]

#define B_ 2
#define D_ 64
#define H_ 384
#define W_ 768
static constexpr int HW    = H_ * W_;
static constexpr int DPT   = 8;          // disparities per thread
static constexpr int NTY   = 4;          // 4 waves/block -> 32 d per block
static constexpr int WT    = 64;
static constexpr int HSEG  = 16;         // output rows per block
static constexpr int RITER = HSEG + 4;   // 20 streamed input rows (div by 5)
static constexpr int LROW  = 72;         // floats per LDS plane row (288 B)
static constexpr int LRWS  = 34;         // LDS rows: planes dbase..dbase+33
static constexpr int NGRAN = LRWS * 18;  // 612 granules of 16 B per stage
static constexpr int NCH   = 10;         // 1-KiB chunks per stage
static constexpr int LBUF  = NCH * 256;  // 2560 floats per buffer

__device__ __forceinline__ void gld_lds16(const float* g, float* l) {
  __builtin_amdgcn_global_load_lds((const __attribute__((address_space(1))) unsigned int*)g,
                                   (__attribute__((address_space(3))) unsigned int*)l,
                                   16, 0, 0);
}

__global__ __launch_bounds__(256) void lga_pass(const float* __restrict__ src,
                                                const float* __restrict__ wts,
                                                float* __restrict__ dst) {
  __shared__ float cl[2][LBUF];           // 20480 B; write-once per buffer

  const int tx    = threadIdx.x;          // 0..63 (lane; wave = ty)
  const int ty    = threadIdx.y;          // 0..3
  const int bx    = blockIdx.x;
  const int w0    = bx * WT, w = w0 + tx;
  const int hs    = blockIdx.y * HSEG;
  const int b     = blockIdx.z >> 1;
  const int dhalf = blockIdx.z & 1;
  const int dbase = dhalf * 32 - 1;       // plane held in LDS row 0
  const int d0    = dhalf * 32 + ty * DPT;

  const float* sb  = src + (size_t)b * D_ * HW;
  const float* wtb = wts + (size_t)b * 75 * HW;

  const bool has_lo = (d0 > 0);
  const bool has_hi = (d0 + DPT < D_);
  const bool edge   = (bx == 0) || (bx == W_ / WT - 1);

  // stage one input row: LDS rows 0..33 <- planes clamp(dbase+p, 0, 63)
  auto stage = [&](int buf, int h_in) {
#pragma unroll
    for (int q = 0; q < 3; ++q) {
      const int c = ty + q * 4;                     // wave-uniform chunk id
      if (c < NCH) {
        int G = c * 64 + tx;                        // granule id
        G = G > NGRAN - 1 ? NGRAN - 1 : G;          // clamp tail (slack area)
        const int p  = G / 18;                      // LDS row
        const int k  = G - p * 18;                  // granule within row
        int pd = dbase + p;                         // source plane
        pd = pd < 0 ? 0 : (pd > D_ - 1 ? D_ - 1 : pd);
        long idx = (long)pd * HW + (long)h_in * W_ + (w0 - 4) + (k << 2);
        idx = idx < 0 ? 0 : idx;
        const long mx = (long)D_ * HW - 4;
        idx = idx > mx ? mx : idx;
        gld_lds16(sb + idx, &cl[buf][c * 256]);
      }
    }
  };

  // prologue: stage input row hs-2 into buf 0
  {
    const int h0 = hs - 2;
    if (h0 >= 0) stage(0, h0);
  }
  __syncthreads();

  float acc[5][DPT];
#pragma unroll
  for (int s = 0; s < 5; ++s)
#pragma unroll
    for (int k = 0; k < DPT; ++k) acc[s][k] = 0.f;

  int n = 0;
#pragma unroll 1
  for (int rb = 0; rb < RITER; rb += 5) {
#pragma unroll
    for (int u = 0; u < 5; ++u) {                   // u compile-time (unrolled)
      const int r = rb + u;                         // rb%5==0 -> phys slot = u

      // ---- 1. batch weight prefetch: all valid slots, earliest-consumed first
      float W[75];
#pragma unroll
      for (int s = 0; s < 5; ++s) {
        if ((unsigned)(r - 4 + s) < (unsigned)HSEG) {     // block-uniform
          const int o     = hs + r - 4 + s;
          const int ib    = (4 - s) * 5;
          const float* wr = wtb + (size_t)o * W_;         // uniform row base
#pragma unroll
          for (int g = 0; g < 3; ++g)
#pragma unroll
            for (int j = 0; j < 5; ++j)
              W[s * 15 + g * 5 + j] = wr[(size_t)(ib + j + 25 * g) * HW + w];
        }
      }

      // ---- 2. async stage of next input row into the other buffer
      if (r + 1 < RITER) {
        const int h_nx = hs - 2 + r + 1;
        if ((unsigned)h_nx < (unsigned)H_) stage(n ^ 1, h_nx);
      }

      // ---- 3. LDS -> vv; masks only where needed (edge blocks / d-edge waves)
      const int  h_in = hs - 2 + r;
      const bool hv   = (unsigned)h_in < (unsigned)H_;    // block-uniform
      float vv[5][DPT + 2];
      if (hv) {
        const float* vbase = cl[n] + ty * DPT * LROW + tx + 2;
        if (!edge) {                                      // interior: no lane masks
#pragma unroll
          for (int j = 0; j < 5; ++j)
#pragma unroll
            for (int m = 0; m < DPT + 2; ++m)
              vv[j][m] = vbase[m * LROW + j];
          if (!has_lo) {                                  // uniform wave branch
#pragma unroll
            for (int j = 0; j < 5; ++j) vv[j][0] = 0.f;
          }
          if (!has_hi) {
#pragma unroll
            for (int j = 0; j < 5; ++j) vv[j][DPT + 1] = 0.f;
          }
        } else {
#pragma unroll
          for (int j = 0; j < 5; ++j) {
            const bool wokj = (unsigned)(w + j - 2) < (unsigned)W_;
#pragma unroll
            for (int m = 0; m < DPT + 2; ++m) {
              const float v = vbase[m * LROW + j];
              bool ok = wokj;
              if (m == 0)       ok = ok && has_lo;
              if (m == DPT + 1) ok = ok && has_hi;
              vv[j][m] = ok ? v : 0.f;
            }
          }
        }
      }

      // ---- 4. per-slot FMAs: logical slot s -> physical acc[(u+s)%5]
      //         (output row hs+r-4+s, tap row 4-s); all indices static.
#pragma unroll
      for (int s = 0; s < 5; ++s) {
        if (hv && (unsigned)(r - 4 + s) < (unsigned)HSEG) {
          float (&a)[DPT] = acc[(u + s) % 5];
#pragma unroll
          for (int j = 0; j < 5; ++j)
#pragma unroll
            for (int k = 0; k < DPT; ++k)
              a[k] = fmaf(W[s * 15 + j],      vv[j][k],
                     fmaf(W[s * 15 + 5 + j],  vv[j][k + 1],
                     fmaf(W[s * 15 + 10 + j], vv[j][k + 2], a[k])));
        }
      }

      // ---- 5. physical slot u completes at iter r -> write row hs+r-4, zero it
      if (r >= 4) {
        const int o = hs + r - 4;
#pragma unroll
        for (int k = 0; k < DPT; ++k) {
          float* dp = dst + (((size_t)b * D_ + d0 + k) * H_ + o) * W_;
          dp[w] = acc[u][k];
        }
#pragma unroll
        for (int k = 0; k < DPT; ++k) acc[u][k] = 0.f;
      }

      __syncthreads();   // drains staged loads; swap buffers (4-wave group)
      n ^= 1;
    }
  }
}

extern "C" void kernel_launch(void* const* d_in, const int* in_sizes, int n_in,
                              void* d_out, int out_size, void* d_ws, size_t ws_size,
                              hipStream_t stream) {
  const float* cost = (const float*)d_in[0];
  const float* wts  = (const float*)d_in[1];
  float* out = (float*)d_out;
  float* ws  = (float*)d_ws;

  dim3 grid(W_ / WT, H_ / HSEG, B_ * 2);   // 12 x 24 x 4 = 1152 blocks
  dim3 block(WT, NTY);                     // 64 x 4 = 256 threads

  lga_pass<<<grid, block, 0, stream>>>(cost, wts, out);
  lga_pass<<<grid, block, 0, stream>>>(out, wts, ws);
  lga_pass<<<grid, block, 0, stream>>>(ws, wts, out);
}

// Round 22
// 581.030 us; speedup vs baseline: 1.3952x; 1.3952x over previous
//
#include <hip/hip_runtime.h>

// LGA3: 3 chained local-guided-aggregation passes, rolling-accumulator stencil.
// R13 d-split shell, UNCHANGED BODY (4-wave 256-thr independent blocks, 32 d
// each, DPT=8, double-buffered cost LDS via global_load_lds, 75 weights
// batch-loaded to registers, rotation loop, one __syncthreads per iter).
// Single change vs R13: HSEG 8 -> 16 (h-halo overhead 1.5x -> 1.25x).
// cost [B=2, D=64, H=384, W=768] fp32, weights [B, 75, H, W] fp32.
// out[b,d,h,w] = sum_{i,j in 5x5} w0*c[d-1,h+i-2,w+j-2] + w1*c[d,..] + w2*c[d+1,..]

#define B_ 2
#define D_ 64
#define H_ 384
#define W_ 768
static constexpr int HW    = H_ * W_;
static constexpr int DPT   = 8;          // disparities per thread
static constexpr int NTY   = 4;          // 4 waves/block -> 32 d per block
static constexpr int WT    = 64;
static constexpr int HSEG  = 16;         // output rows per block (R13: 8)
static constexpr int RITER = HSEG + 4;   // 20 streamed input rows
static constexpr int LROW  = 72;         // floats per LDS plane row (288 B)
static constexpr int LRWS  = 34;         // LDS rows: planes dbase..dbase+33
static constexpr int NGRAN = LRWS * 18;  // 612 granules of 16 B per stage
static constexpr int NCH   = 10;         // 1-KiB chunks per stage
static constexpr int LBUF  = NCH * 256;  // 2560 floats per buffer

__device__ __forceinline__ void gld_lds16(const float* g, float* l) {
  __builtin_amdgcn_global_load_lds((const __attribute__((address_space(1))) unsigned int*)g,
                                   (__attribute__((address_space(3))) unsigned int*)l,
                                   16, 0, 0);
}

__global__ __launch_bounds__(256) void lga_pass(const float* __restrict__ src,
                                                const float* __restrict__ wts,
                                                float* __restrict__ dst) {
  __shared__ float cl[2][LBUF];           // 20480 B; write-once per buffer

  const int tx    = threadIdx.x;          // 0..63 (lane; wave = ty)
  const int ty    = threadIdx.y;          // 0..3
  const int bx    = blockIdx.x;
  const int w0    = bx * WT, w = w0 + tx;
  const int hs    = blockIdx.y * HSEG;
  const int b     = blockIdx.z >> 1;
  const int dhalf = blockIdx.z & 1;
  const int dbase = dhalf * 32 - 1;       // plane held in LDS row 0
  const int d0    = dhalf * 32 + ty * DPT;

  const float* sb  = src + (size_t)b * D_ * HW;
  const float* wtb = wts + (size_t)b * 75 * HW;

  const bool has_lo = (d0 > 0);
  const bool has_hi = (d0 + DPT < D_);
  const bool edge   = (bx == 0) || (bx == W_ / WT - 1);

  // stage one input row: LDS rows 0..33 <- planes clamp(dbase+p, 0, 63)
  auto stage = [&](int buf, int h_in) {
#pragma unroll
    for (int q = 0; q < 3; ++q) {
      const int c = ty + q * 4;                     // wave-uniform chunk id
      if (c < NCH) {
        int G = c * 64 + tx;                        // granule id
        G = G > NGRAN - 1 ? NGRAN - 1 : G;          // clamp tail (slack area)
        const int p  = G / 18;                      // LDS row
        const int k  = G - p * 18;                  // granule within row
        int pd = dbase + p;                         // source plane
        pd = pd < 0 ? 0 : (pd > D_ - 1 ? D_ - 1 : pd);
        long idx = (long)pd * HW + (long)h_in * W_ + (w0 - 4) + (k << 2);
        idx = idx < 0 ? 0 : idx;
        const long mx = (long)D_ * HW - 4;
        idx = idx > mx ? mx : idx;
        gld_lds16(sb + idx, &cl[buf][c * 256]);
      }
    }
  };

  // prologue: stage input row hs-2 into buf 0
  {
    const int h0 = hs - 2;
    if (h0 >= 0) stage(0, h0);
  }
  __syncthreads();

  float acc[5][DPT];
#pragma unroll
  for (int s = 0; s < 5; ++s)
#pragma unroll
    for (int k = 0; k < DPT; ++k) acc[s][k] = 0.f;

  int n = 0;
#pragma unroll 1
  for (int r = 0; r < RITER; ++r) {
    // ---- 1. batch weight prefetch: all 75 loads, slot order (earliest use first)
    float W[75];
#pragma unroll
    for (int s = 0; s < 5; ++s) {
      if ((unsigned)(r - 4 + s) < (unsigned)HSEG) {       // block-uniform
        const int o     = hs + r - 4 + s;
        const int ib    = (4 - s) * 5;
        const float* wr = wtb + (size_t)o * W_;           // uniform row base
#pragma unroll
        for (int g = 0; g < 3; ++g)
#pragma unroll
          for (int j = 0; j < 5; ++j)
            W[s * 15 + g * 5 + j] = wr[(size_t)(ib + j + 25 * g) * HW + w];
      }
    }

    // ---- 2. async stage of next input row into the other buffer
    if (r + 1 < RITER) {
      const int h_nx = hs - 2 + r + 1;
      if ((unsigned)h_nx < (unsigned)H_) stage(n ^ 1, h_nx);
    }

    // ---- 3. LDS -> vv; masks only where needed (edge blocks / d-edge waves)
    const int  h_in = hs - 2 + r;
    const bool hv   = (unsigned)h_in < (unsigned)H_;      // block-uniform
    float vv[5][DPT + 2];
    if (hv) {
      const float* vbase = cl[n] + ty * DPT * LROW + tx + 2;
      if (!edge) {                                        // interior: no lane masks
#pragma unroll
        for (int j = 0; j < 5; ++j)
#pragma unroll
          for (int m = 0; m < DPT + 2; ++m)
            vv[j][m] = vbase[m * LROW + j];
        if (!has_lo) {                                    // uniform wave branch
#pragma unroll
          for (int j = 0; j < 5; ++j) vv[j][0] = 0.f;
        }
        if (!has_hi) {
#pragma unroll
          for (int j = 0; j < 5; ++j) vv[j][DPT + 1] = 0.f;
        }
      } else {
#pragma unroll
        for (int j = 0; j < 5; ++j) {
          const bool wokj = (unsigned)(w + j - 2) < (unsigned)W_;
#pragma unroll
          for (int m = 0; m < DPT + 2; ++m) {
            const float v = vbase[m * LROW + j];
            bool ok = wokj;
            if (m == 0)       ok = ok && has_lo;
            if (m == DPT + 1) ok = ok && has_hi;
            vv[j][m] = ok ? v : 0.f;
          }
        }
      }
    }

    // ---- 4. per-slot FMAs (slot s -> output row hs+r-4+s, tap row 4-s)
#pragma unroll
    for (int s = 0; s < 5; ++s) {
      if (hv && (unsigned)(r - 4 + s) < (unsigned)HSEG) {
#pragma unroll
        for (int j = 0; j < 5; ++j)
#pragma unroll
          for (int k = 0; k < DPT; ++k)
            acc[s][k] = fmaf(W[s * 15 + j],      vv[j][k],
                        fmaf(W[s * 15 + 5 + j],  vv[j][k + 1],
                        fmaf(W[s * 15 + 10 + j], vv[j][k + 2], acc[s][k])));
      }
    }

    // ---- 5. slot 0 complete -> write output row hs+r-4
    if (r >= 4) {
      const int o = hs + r - 4;
#pragma unroll
      for (int k = 0; k < DPT; ++k) {
        float* dp = dst + (((size_t)b * D_ + d0 + k) * H_ + o) * W_;
        dp[w] = acc[0][k];
      }
    }

    // ---- 6. rotate accumulator slots (static indices)
#pragma unroll
    for (int s = 0; s < 4; ++s)
#pragma unroll
      for (int k = 0; k < DPT; ++k) acc[s][k] = acc[s + 1][k];
#pragma unroll
    for (int k = 0; k < DPT; ++k) acc[4][k] = 0.f;

    __syncthreads();   // drains staged loads; swap buffers (4-wave group only)
    n ^= 1;
  }
}

extern "C" void kernel_launch(void* const* d_in, const int* in_sizes, int n_in,
                              void* d_out, int out_size, void* d_ws, size_t ws_size,
                              hipStream_t stream) {
  const float* cost = (const float*)d_in[0];
  const float* wts  = (const float*)d_in[1];
  float* out = (float*)d_out;
  float* ws  = (float*)d_ws;

  dim3 grid(W_ / WT, H_ / HSEG, B_ * 2);   // 12 x 24 x 4 = 1152 blocks
  dim3 block(WT, NTY);                     // 64 x 4 = 256 threads

  lga_pass<<<grid, block, 0, stream>>>(cost, wts, out);
  lga_pass<<<grid, block, 0, stream>>>(out, wts, ws);
  lga_pass<<<grid, block, 0, stream>>>(ws, wts, out);
}